// Round 1
// baseline (836.608 us; speedup 1.0000x reference)
//
#include <hip/hip_runtime.h>
#include <hip/hip_bf16.h>
#include <stdint.h>

#define M_DIM 4096
#define K_DIM 4096
#define N_DIM 11008

typedef __bf16 bf16_t;
typedef __bf16 bf16x4 __attribute__((ext_vector_type(4)));
typedef __bf16 bf16x8 __attribute__((ext_vector_type(8)));
typedef float floatx4 __attribute__((ext_vector_type(4)));

// ---------------------------------------------------------------------------
// k_prescale: xs[m,k] = bf16(x[m,k] * s[k/64]);  crow[m] = sum_k x[m,k]*s*zp
// One block per row, 256 threads, float4 loads.
// ---------------------------------------------------------------------------
__global__ __launch_bounds__(256) void k_prescale(
    const float* __restrict__ x,
    const float* __restrict__ scales,
    const float* __restrict__ zps,
    bf16_t* __restrict__ xs,
    float* __restrict__ crow)
{
    const int m = blockIdx.x;
    const int t = threadIdx.x;
    const float4* xr = (const float4*)(x + (size_t)m * K_DIM);
    bf16x4* xo = (bf16x4*)(xs + (size_t)m * K_DIM);
    float acc = 0.f;
#pragma unroll
    for (int i = 0; i < 4; ++i) {
        const int idx = i * 256 + t;          // float4 index within row
        const int g = (idx * 4) >> 6;         // group of these 4 elements
        const float s = scales[g];
        const float tz = s * zps[g];
        const float4 v = xr[idx];
        bf16x4 o;
        o[0] = (bf16_t)(v.x * s);
        o[1] = (bf16_t)(v.y * s);
        o[2] = (bf16_t)(v.z * s);
        o[3] = (bf16_t)(v.w * s);
        xo[idx] = o;
        acc += (v.x + v.y + v.z + v.w) * tz;
    }
    // block reduce (4 waves)
#pragma unroll
    for (int off = 32; off > 0; off >>= 1) acc += __shfl_down(acc, off, 64);
    __shared__ float wsum[4];
    const int wave = t >> 6, lane = t & 63;
    if (lane == 0) wsum[wave] = acc;
    __syncthreads();
    if (t == 0) crow[m] = wsum[0] + wsum[1] + wsum[2] + wsum[3];
}

// ---------------------------------------------------------------------------
// k_decode: packed int32 [N][K/2] (1 byte of 2 nibbles each) -> bf16 W[N][K]
// thread: 4 int32 (int4 load) -> 8 bf16 (16B store). low nibble = even col.
// signed int4 via (v^8)-8.
// ---------------------------------------------------------------------------
__global__ __launch_bounds__(256) void k_decode(
    const int* __restrict__ pw, bf16_t* __restrict__ W)
{
    const size_t tid = (size_t)blockIdx.x * 256 + threadIdx.x;
    const int4 v = ((const int4*)pw)[tid];
    bf16x8 o;
    int b;
    b = v.x & 255; o[0] = (bf16_t)(float)(((b & 15) ^ 8) - 8); o[1] = (bf16_t)(float)((((b >> 4) & 15) ^ 8) - 8);
    b = v.y & 255; o[2] = (bf16_t)(float)(((b & 15) ^ 8) - 8); o[3] = (bf16_t)(float)((((b >> 4) & 15) ^ 8) - 8);
    b = v.z & 255; o[4] = (bf16_t)(float)(((b & 15) ^ 8) - 8); o[5] = (bf16_t)(float)((((b >> 4) & 15) ^ 8) - 8);
    b = v.w & 255; o[6] = (bf16_t)(float)(((b & 15) ^ 8) - 8); o[7] = (bf16_t)(float)((((b >> 4) & 15) ^ 8) - 8);
    ((bf16x8*)W)[tid] = o;
}

// ---------------------------------------------------------------------------
// k_gemm: out[m,n] = sum_k xs[m,k]*W[n,k] + bias[n] - crow[m]
// m97-style: 128x128 tile, BK=32, 256 threads (4 waves, 2x2 of 64x64 wave
// tiles), 16x16x32 bf16 MFMA, global_load_lds width=16 staging.
// LDS layout row-major [128][32] bf16, no padding (global_load_lds constraint).
// ---------------------------------------------------------------------------
__global__ __launch_bounds__(256) void k_gemm(
    const bf16_t* __restrict__ A,     // xs [M][K]
    const bf16_t* __restrict__ B,     // W  [N][K]
    const float* __restrict__ bias,
    const float* __restrict__ crow,
    float* __restrict__ out)
{
    __shared__ bf16_t sA[128 * 32];
    __shared__ bf16_t sB[128 * 32];

    const int t = threadIdx.x;
    const int wave = t >> 6;
    const int lane = t & 63;
    const int fm = lane & 15;
    const int quad = lane >> 4;

    const int nBase = blockIdx.x * 128;
    const int mBase = blockIdx.y * 128;

    // staging: chunk c = r*256 + t ; row = c>>2 ; kchunk = c&3 (16B chunks)
    const int c0 = t;
    const int c1 = 256 + t;
    const size_t gA0 = (size_t)(mBase + (c0 >> 2)) * K_DIM + (size_t)(c0 & 3) * 8;
    const size_t gA1 = (size_t)(mBase + (c1 >> 2)) * K_DIM + (size_t)(c1 & 3) * 8;
    const size_t gB0 = (size_t)(nBase + (c0 >> 2)) * K_DIM + (size_t)(c0 & 3) * 8;
    const size_t gB1 = (size_t)(nBase + (c1 >> 2)) * K_DIM + (size_t)(c1 & 3) * 8;

    // wave-uniform LDS bases (HW adds lane*16B)
    bf16_t* lA0 = sA + wave * 512;
    bf16_t* lA1 = sA + 2048 + wave * 512;
    bf16_t* lB0 = sB + wave * 512;
    bf16_t* lB1 = sB + 2048 + wave * 512;

    const int wm = (wave >> 1) * 64;   // wave tile origin in block tile
    const int wn = (wave & 1) * 64;

    floatx4 acc[4][4];
#pragma unroll
    for (int mi = 0; mi < 4; ++mi)
#pragma unroll
        for (int ni = 0; ni < 4; ++ni)
            acc[mi][ni] = (floatx4){0.f, 0.f, 0.f, 0.f};

    for (int kt = 0; kt < K_DIM / 32; ++kt) {
        const size_t kOff = (size_t)kt * 32;
        __syncthreads();   // prior iter's ds_reads done before overwrite
        __builtin_amdgcn_global_load_lds(
            (__attribute__((address_space(1))) void*)(A + gA0 + kOff),
            (__attribute__((address_space(3))) void*)lA0, 16, 0, 0);
        __builtin_amdgcn_global_load_lds(
            (__attribute__((address_space(1))) void*)(A + gA1 + kOff),
            (__attribute__((address_space(3))) void*)lA1, 16, 0, 0);
        __builtin_amdgcn_global_load_lds(
            (__attribute__((address_space(1))) void*)(B + gB0 + kOff),
            (__attribute__((address_space(3))) void*)lB0, 16, 0, 0);
        __builtin_amdgcn_global_load_lds(
            (__attribute__((address_space(1))) void*)(B + gB1 + kOff),
            (__attribute__((address_space(3))) void*)lB1, 16, 0, 0);
        __builtin_amdgcn_s_waitcnt(0);   // drain vmcnt before barrier
        __syncthreads();

        bf16x8 af[4], bfr[4];
#pragma unroll
        for (int mi = 0; mi < 4; ++mi)
            af[mi] = *(const bf16x8*)(sA + (wm + mi * 16 + fm) * 32 + quad * 8);
#pragma unroll
        for (int ni = 0; ni < 4; ++ni)
            bfr[ni] = *(const bf16x8*)(sB + (wn + ni * 16 + fm) * 32 + quad * 8);
#pragma unroll
        for (int mi = 0; mi < 4; ++mi)
#pragma unroll
            for (int ni = 0; ni < 4; ++ni)
                acc[mi][ni] = __builtin_amdgcn_mfma_f32_16x16x32_bf16(
                    af[mi], bfr[ni], acc[mi][ni], 0, 0, 0);
    }

    // epilogue: + bias[n] - crow[m]; C/D map: col=lane&15, row=quad*4+reg
#pragma unroll
    for (int mi = 0; mi < 4; ++mi) {
        const int m0 = mBase + wm + mi * 16 + quad * 4;
        float cr[4];
#pragma unroll
        for (int r = 0; r < 4; ++r) cr[r] = crow[m0 + r];
#pragma unroll
        for (int ni = 0; ni < 4; ++ni) {
            const int n = nBase + wn + ni * 16 + fm;
            const float bn = bias[n];
#pragma unroll
            for (int r = 0; r < 4; ++r)
                out[(size_t)(m0 + r) * N_DIM + n] = acc[mi][ni][r] + bn - cr[r];
        }
    }
}

// ---------------------------------------------------------------------------
extern "C" void kernel_launch(void* const* d_in, const int* in_sizes, int n_in,
                              void* d_out, int out_size, void* d_ws, size_t ws_size,
                              hipStream_t stream)
{
    const float* x      = (const float*)d_in[0];
    const int*   pw     = (const int*)d_in[1];
    const float* scales = (const float*)d_in[2];
    const float* zps    = (const float*)d_in[3];
    const float* bias   = (const float*)d_in[4];
    float* out = (float*)d_out;

    char* ws = (char*)d_ws;
    bf16_t* xs   = (bf16_t*)ws;                          // 4096*4096*2 = 33554432 B
    float*  crow = (float*)(ws + 33554432);              // 4096*4      = 16384 B
    bf16_t* W    = (bf16_t*)(ws + 33570816);             // 11008*4096*2 = 90177536 B

    hipLaunchKernelGGL(k_prescale, dim3(M_DIM), dim3(256), 0, stream,
                       x, scales, zps, xs, crow);
    // N*K/2 int32 = 22544384 ; /4 per thread /256 per block = 22016 blocks
    hipLaunchKernelGGL(k_decode, dim3(22016), dim3(256), 0, stream, pw, W);
    hipLaunchKernelGGL(k_gemm, dim3(N_DIM / 128, M_DIM / 128), dim3(256), 0, stream,
                       W ? (const bf16_t*)xs : (const bf16_t*)xs, (const bf16_t*)W,
                       bias, crow, out);
}

// Round 2
// 779.079 us; speedup vs baseline: 1.0738x; 1.0738x over previous
//
#include <hip/hip_runtime.h>
#include <hip/hip_bf16.h>
#include <stdint.h>

#define M_DIM 4096
#define K_DIM 4096
#define N_DIM 11008
#define BK 64

typedef __bf16 bf16_t;
typedef __bf16 bf16x4 __attribute__((ext_vector_type(4)));
typedef __bf16 bf16x8 __attribute__((ext_vector_type(8)));
typedef float floatx4 __attribute__((ext_vector_type(4)));

// ---------------------------------------------------------------------------
// k_prescale: xs[m,k] = bf16(x[m,k] * s[k/64]);
//             crow[m] = sum_k float(xs[m,k]) * (zp[g] + 136)
// The +136 folds the w-magic offset (GEMM feeds w4+136 to the MFMA; see
// k_gemm unpack). Using the bf16-rounded xs in crow makes the 136-term cancel
// exactly against the GEMM side.
// ---------------------------------------------------------------------------
__global__ __launch_bounds__(256) void k_prescale(
    const float* __restrict__ x,
    const float* __restrict__ scales,
    const float* __restrict__ zps,
    bf16_t* __restrict__ xs,
    float* __restrict__ crow)
{
    const int m = blockIdx.x;
    const int t = threadIdx.x;
    const float4* xr = (const float4*)(x + (size_t)m * K_DIM);
    bf16x4* xo = (bf16x4*)(xs + (size_t)m * K_DIM);
    float acc = 0.f;
#pragma unroll
    for (int i = 0; i < 4; ++i) {
        const int idx = i * 256 + t;          // float4 index within row
        const int g = (idx * 4) >> 6;         // group of these 4 elements
        const float s = scales[g];
        const float tz = zps[g] + 136.0f;
        const float4 v = xr[idx];
        bf16x4 o;
        o[0] = (bf16_t)(v.x * s);
        o[1] = (bf16_t)(v.y * s);
        o[2] = (bf16_t)(v.z * s);
        o[3] = (bf16_t)(v.w * s);
        xo[idx] = o;
        acc += ((float)o[0] + (float)o[1] + (float)o[2] + (float)o[3]) * tz;
    }
#pragma unroll
    for (int off = 32; off > 0; off >>= 1) acc += __shfl_down(acc, off, 64);
    __shared__ float wsum[4];
    const int wave = t >> 6, lane = t & 63;
    if (lane == 0) wsum[wave] = acc;
    __syncthreads();
    if (t == 0) crow[m] = wsum[0] + wsum[1] + wsum[2] + wsum[3];
}

// ---------------------------------------------------------------------------
// k_gemm with fused int4 decode.
//   out[m,n] = sum_k xs[m,k]*(w4[n,k]+136) + bias[n] - crow[m]
// Tiles: 128x128 block, BK=64, 4 waves in 2x2 of 64x64, 16x16x32 bf16 MFMA.
// LDS: sA/sB bf16 [128 rows][64 cols] = 16 KB each, rotation-swizzled:
//   physical 16B-chunk sc of row r holds logical chunk (sc + r) & 7
//   (reader: sc = (lc - r) & 7)  -> conflict-free b128 reads AND writes.
// A staged via global_load_lds width=16 (4 instr/wave/iter).
// B: packed int32 (1 byte = 2 nibbles each) loaded to regs (coalesced 16B),
//   unpacked via v_perm magic: bf16(0x4300|(n^8)) = (n^8)+128 = w4+136,
//   then ds_write_b128 into sB. Unpack cost ~12 VALU per 8 weights, once per
//   block (stage-side), overlapping the A DMA latency.
// ---------------------------------------------------------------------------
__global__ __launch_bounds__(256) void k_gemm(
    const bf16_t* __restrict__ A,     // xs [M][K] bf16
    const int* __restrict__ Bp,       // packed_w [N][K/2] int32 (low byte)
    const float* __restrict__ bias,
    const float* __restrict__ crow,
    float* __restrict__ out)
{
    __shared__ bf16_t sA[128 * BK];   // 16 KB
    __shared__ bf16_t sB[128 * BK];   // 16 KB

    const int t = threadIdx.x;
    const int wave = t >> 6;
    const int lane = t & 63;
    const int fm = lane & 15;
    const int quad = lane >> 4;

    const int nBase = blockIdx.x * 128;
    const int mBase = blockIdx.y * 128;

    // ---- A staging descriptors (16B chunks; 1024 chunks per tile) ----
    // chunk c: row = c>>3, physical sc = c&7, global col gc = (sc+row)&7
    size_t gA[4];
    bf16_t* lA[4];
#pragma unroll
    for (int i = 0; i < 4; ++i) {
        const int c = i * 256 + t;
        const int row = c >> 3;
        const int gc = ((c & 7) + row) & 7;
        gA[i] = (size_t)(mBase + row) * K_DIM + (size_t)(gc << 3);
        lA[i] = sA + (size_t)((i * 256 + wave * 64) << 3);  // wave-uniform base
    }

    // ---- B staging descriptors ----
    // int4-load f = j*256+t: row tr = f>>3, chunk-in-row pc = f&7
    // (8 lanes cover one row's 128 B contiguously -> coalesced)
    size_t gB[4];
    int ldsB[4];
#pragma unroll
    for (int j = 0; j < 4; ++j) {
        const int f = j * 256 + t;
        const int tr = f >> 3;
        const int pc = f & 7;
        gB[j] = (size_t)(nBase + tr) * (K_DIM / 2) + (size_t)(pc << 2); // int32 units
        const int sc = (pc - tr) & 7;   // rotation swizzle (write side)
        ldsB[j] = tr * 64 + sc * 8;     // element offset
    }

    const int wm = (wave >> 1) * 64;
    const int wn = (wave & 1) * 64;

    floatx4 acc[4][4];
#pragma unroll
    for (int mi = 0; mi < 4; ++mi)
#pragma unroll
        for (int ni = 0; ni < 4; ++ni)
            acc[mi][ni] = (floatx4){0.f, 0.f, 0.f, 0.f};

    const uint32_t kMag = 0x43434343u;

    for (int kt = 0; kt < K_DIM / BK; ++kt) {
        // B packed loads first (no LDS touch; oldest in vmcnt queue so the
        // unpack's wait leaves the A DMAs in flight)
        int4 bp[4];
#pragma unroll
        for (int j = 0; j < 4; ++j)
            bp[j] = *(const int4*)(Bp + gB[j] + (size_t)kt * (BK / 2));

        __syncthreads();   // prior iter's frag reads done before overwrite

#pragma unroll
        for (int i = 0; i < 4; ++i)
            __builtin_amdgcn_global_load_lds(
                (const __attribute__((address_space(1))) void*)(A + gA[i] + (size_t)kt * BK),
                (__attribute__((address_space(3))) void*)lA[i], 16, 0, 0);

        // unpack B: 4 int32 (1 byte each) -> 8 bf16 weights (= w4 + 136)
#pragma unroll
        for (int j = 0; j < 4; ++j) {
            uint32_t p0 = __builtin_amdgcn_perm((uint32_t)bp[j].y, (uint32_t)bp[j].x, 0x0C0C0400u); // [x0,y0,0,0]
            uint32_t p1 = __builtin_amdgcn_perm((uint32_t)bp[j].w, (uint32_t)bp[j].z, 0x04000C0Cu); // [0,0,z0,w0]
            uint32_t bb = (p0 | p1) ^ 0x88888888u;          // nibbles n^8
            uint32_t lo = bb & 0x0F0F0F0Fu;                 // even-k weights
            uint32_t hi = (bb >> 4) & 0x0F0F0F0Fu;          // odd-k weights
            uint32_t m0 = __builtin_amdgcn_perm(hi, lo, 0x05010400u);  // [l0,h0,l1,h1]
            uint32_t m1 = __builtin_amdgcn_perm(hi, lo, 0x07030602u);  // [l2,h2,l3,h3]
            uint4 o;
            o.x = __builtin_amdgcn_perm(kMag, m0, 0x04010400u);  // bf16x2 (w0,w1)
            o.y = __builtin_amdgcn_perm(kMag, m0, 0x04030402u);  // (w2,w3)
            o.z = __builtin_amdgcn_perm(kMag, m1, 0x04010400u);  // (w4,w5)
            o.w = __builtin_amdgcn_perm(kMag, m1, 0x04030402u);  // (w6,w7)
            *(uint4*)(sB + ldsB[j]) = o;                          // ds_write_b128
        }

        __builtin_amdgcn_s_waitcnt(0);   // drain A DMA (+ lds writes)
        __syncthreads();

#pragma unroll
        for (int kh = 0; kh < 2; ++kh) {
            bf16x8 af[4], bfm[4];
#pragma unroll
            for (int mi = 0; mi < 4; ++mi) {
                const int r = wm + mi * 16 + fm;
                const int sc = ((kh * 4 + quad) - r) & 7;
                af[mi] = *(const bf16x8*)(sA + r * 64 + sc * 8);
            }
#pragma unroll
            for (int ni = 0; ni < 4; ++ni) {
                const int r = wn + ni * 16 + fm;
                const int sc = ((kh * 4 + quad) - r) & 7;
                bfm[ni] = *(const bf16x8*)(sB + r * 64 + sc * 8);
            }
#pragma unroll
            for (int mi = 0; mi < 4; ++mi)
#pragma unroll
                for (int ni = 0; ni < 4; ++ni)
                    acc[mi][ni] = __builtin_amdgcn_mfma_f32_16x16x32_bf16(
                        af[mi], bfm[ni], acc[mi][ni], 0, 0, 0);
        }
    }

    // epilogue: + bias[n] - crow[m]; C/D map: col=lane&15, row=quad*4+reg
#pragma unroll
    for (int mi = 0; mi < 4; ++mi) {
        const int m0 = mBase + wm + mi * 16 + quad * 4;
        float cr[4];
#pragma unroll
        for (int r = 0; r < 4; ++r) cr[r] = crow[m0 + r];
#pragma unroll
        for (int ni = 0; ni < 4; ++ni) {
            const int n = nBase + wn + ni * 16 + fm;
            const float bn = bias[n];
#pragma unroll
            for (int r = 0; r < 4; ++r)
                out[(size_t)(m0 + r) * N_DIM + n] = acc[mi][ni][r] + bn - cr[r];
        }
    }
}

// ---------------------------------------------------------------------------
extern "C" void kernel_launch(void* const* d_in, const int* in_sizes, int n_in,
                              void* d_out, int out_size, void* d_ws, size_t ws_size,
                              hipStream_t stream)
{
    const float* x      = (const float*)d_in[0];
    const int*   pw     = (const int*)d_in[1];
    const float* scales = (const float*)d_in[2];
    const float* zps    = (const float*)d_in[3];
    const float* bias   = (const float*)d_in[4];
    float* out = (float*)d_out;

    char* ws = (char*)d_ws;
    bf16_t* xs   = (bf16_t*)ws;               // 4096*4096*2 = 33554432 B
    float*  crow = (float*)(ws + 33554432);   // 4096*4      = 16384 B

    hipLaunchKernelGGL(k_prescale, dim3(M_DIM), dim3(256), 0, stream,
                       x, scales, zps, xs, crow);
    hipLaunchKernelGGL(k_gemm, dim3(N_DIM / 128, M_DIM / 128), dim3(256), 0, stream,
                       (const bf16_t*)xs, pw, bias, crow, out);
}

// Round 3
// 760.522 us; speedup vs baseline: 1.1000x; 1.0244x over previous
//
#include <hip/hip_runtime.h>
#include <hip/hip_bf16.h>
#include <stdint.h>

#define M_DIM 4096
#define K_DIM 4096
#define N_DIM 11008
#define BK 64

typedef __bf16 bf16_t;
typedef __bf16 bf16x8 __attribute__((ext_vector_type(8)));
typedef float floatx4 __attribute__((ext_vector_type(4)));

// ---------------------------------------------------------------------------
// k_prescale: xs[m, perm(k)] = bf16(x[m,k] * s[k/64]);
//             crow[m] = sum_k float(xs) * (zp[g] + 136)
// k-permutation within each aligned 8-group: slots (0,2,4,6,1,3,5,7) ->
// matches the register-unpacked B fragment order in k_gemm (lo nibbles
// first). Dot products are invariant since A and B use the same order.
// +136 folds the w-magic offset (GEMM feeds w4+136 to the MFMA).
// ---------------------------------------------------------------------------
__global__ __launch_bounds__(256) void k_prescale(
    const float* __restrict__ x,
    const float* __restrict__ scales,
    const float* __restrict__ zps,
    bf16_t* __restrict__ xs,
    float* __restrict__ crow)
{
    const int m = blockIdx.x;
    const int t = threadIdx.x;
    const float4* xr = (const float4*)(x + (size_t)m * K_DIM);
    bf16x8* xo = (bf16x8*)(xs + (size_t)m * K_DIM);
    float acc = 0.f;
#pragma unroll
    for (int i = 0; i < 2; ++i) {
        const int idx = i * 256 + t;          // 8-elem group index (512/row)
        const int g = idx >> 3;               // 64 elems per quant group
        const float s = scales[g];
        const float tz = zps[g] + 136.0f;
        const float4 v0 = xr[2 * idx];
        const float4 v1 = xr[2 * idx + 1];
        bf16x8 o;
        o[0] = (bf16_t)(v0.x * s);  // k+0
        o[1] = (bf16_t)(v0.z * s);  // k+2
        o[2] = (bf16_t)(v1.x * s);  // k+4
        o[3] = (bf16_t)(v1.z * s);  // k+6
        o[4] = (bf16_t)(v0.y * s);  // k+1
        o[5] = (bf16_t)(v0.w * s);  // k+3
        o[6] = (bf16_t)(v1.y * s);  // k+5
        o[7] = (bf16_t)(v1.w * s);  // k+7
        xo[idx] = o;
        float ssum = 0.f;
#pragma unroll
        for (int j = 0; j < 8; ++j) ssum += (float)o[j];
        acc += ssum * tz;
    }
#pragma unroll
    for (int off = 32; off > 0; off >>= 1) acc += __shfl_down(acc, off, 64);
    __shared__ float wsum[4];
    const int wave = t >> 6, lane = t & 63;
    if (lane == 0) wsum[wave] = acc;
    __syncthreads();
    if (t == 0) crow[m] = wsum[0] + wsum[1] + wsum[2] + wsum[3];
}

// ---------------------------------------------------------------------------
// k_gemm, fused int4 decode, B kept entirely in registers.
//   out[m,n] = sum_k xs[m,k]*(w4[n,k]+136) + bias[n] - crow[m]
// Block tile 256x128, BK=64, 4 waves in 2(m)x2(n): wave tile 128x64.
// A: LDS [256][64] bf16 (32 KB), rotation swizzle (phys chunk sc of row r
//    holds logical chunk (sc+r)&7), staged via global_load_lds width=16.
// B: per-lane direct fragment loads: lane(fm,quad) global_load_dwordx4 at
//    row(fm+16ni)*2048 + kpos (int32 units) -> 4 low bytes = 8 nibbles ->
//    v_perm magic bf16(0x43XX) = w4+136, k-order (0,2,4,6,1,3,5,7) to match
//    pre-permuted A. No B LDS traffic at all.
// ---------------------------------------------------------------------------
__device__ __forceinline__ bf16x8 unpack_b(int4 v)
{
    const uint32_t kMag = 0x43434343u;
    uint32_t p0 = __builtin_amdgcn_perm((uint32_t)v.y, (uint32_t)v.x, 0x0C0C0400u); // [b0,b1,0,0]
    uint32_t p1 = __builtin_amdgcn_perm((uint32_t)v.w, (uint32_t)v.z, 0x04000C0Cu); // [0,0,b2,b3]
    uint32_t bb = (p0 | p1) ^ 0x88888888u;          // nibbles n^8
    uint32_t lo = bb & 0x0F0F0F0Fu;                 // even-k weights
    uint32_t hi = (bb >> 4) & 0x0F0F0F0Fu;          // odd-k weights
    union { uint4 u; bf16x8 f; } o;
    o.u.x = __builtin_amdgcn_perm(kMag, lo, 0x04010400u);  // (k0,k2)+136
    o.u.y = __builtin_amdgcn_perm(kMag, lo, 0x04030402u);  // (k4,k6)+136
    o.u.z = __builtin_amdgcn_perm(kMag, hi, 0x04010400u);  // (k1,k3)+136
    o.u.w = __builtin_amdgcn_perm(kMag, hi, 0x04030402u);  // (k5,k7)+136
    return o.f;
}

__global__ __launch_bounds__(256, 2) void k_gemm(
    const bf16_t* __restrict__ A,     // xs [M][K] bf16 (k-permuted in 8-groups)
    const int* __restrict__ Bp,       // packed_w [N][K/2] int32 (low byte)
    const float* __restrict__ bias,
    const float* __restrict__ crow,
    float* __restrict__ out)
{
    __shared__ bf16_t sA[256 * BK];   // 32 KB

    const int t = threadIdx.x;
    const int wave = t >> 6;
    const int lane = t & 63;
    const int fm = lane & 15;
    const int quad = lane >> 4;

    const int nBase = blockIdx.x * 128;
    const int mBase = blockIdx.y * 256;

    // ---- A staging (2048 16B-chunks; 8 per thread) ----
    uint32_t gA[8];                   // element offsets
    int lA[8];                        // wave-uniform LDS element offsets
#pragma unroll
    for (int i = 0; i < 8; ++i) {
        const int c = i * 256 + t;
        const int row = c >> 3;
        const int gc = ((c & 7) + row) & 7;
        gA[i] = (uint32_t)(mBase + row) * K_DIM + (uint32_t)(gc << 3);
        lA[i] = (i * 256 + wave * 64) << 3;
    }

    const int wm = (wave >> 1) * 128;
    const int wn = (wave & 1) * 64;

    // B fragment row offsets (int32 units)
    int bOff[4];
#pragma unroll
    for (int ni = 0; ni < 4; ++ni)
        bOff[ni] = (nBase + wn + ni * 16 + fm) * (K_DIM / 2) + quad * 4;

    floatx4 acc[8][4];
#pragma unroll
    for (int mi = 0; mi < 8; ++mi)
#pragma unroll
        for (int ni = 0; ni < 4; ++ni)
            acc[mi][ni] = (floatx4){0.f, 0.f, 0.f, 0.f};

#pragma unroll 1
    for (int kt = 0; kt < K_DIM / BK; ++kt) {
        // B packed loads (both kh halves) — issued before the DMAs so the
        // unpack's vmcnt wait leaves the A DMAs in flight.
        int4 bp[2][4];
#pragma unroll
        for (int kh = 0; kh < 2; ++kh)
#pragma unroll
            for (int ni = 0; ni < 4; ++ni)
                bp[kh][ni] = *(const int4*)(Bp + bOff[ni] + kt * 32 + kh * 16);

        __syncthreads();   // prior iter's A reads done before overwrite

#pragma unroll
        for (int i = 0; i < 8; ++i)
            __builtin_amdgcn_global_load_lds(
                (const __attribute__((address_space(1))) void*)(A + (size_t)gA[i] + (size_t)kt * BK),
                (__attribute__((address_space(3))) void*)(sA + lA[i]), 16, 0, 0);

        // unpack B in-register while the A DMA is in flight
        bf16x8 bfr[2][4];
#pragma unroll
        for (int kh = 0; kh < 2; ++kh)
#pragma unroll
            for (int ni = 0; ni < 4; ++ni)
                bfr[kh][ni] = unpack_b(bp[kh][ni]);

        __builtin_amdgcn_s_waitcnt(0);   // drain A DMA
        __syncthreads();

#pragma unroll
        for (int kh = 0; kh < 2; ++kh) {
#pragma unroll
            for (int mi = 0; mi < 8; ++mi) {
                const int r = wm + mi * 16 + fm;
                const int sc = ((kh * 4 + quad) - r) & 7;
                const bf16x8 af = *(const bf16x8*)(sA + r * 64 + sc * 8);
#pragma unroll
                for (int ni = 0; ni < 4; ++ni)
                    acc[mi][ni] = __builtin_amdgcn_mfma_f32_16x16x32_bf16(
                        af, bfr[kh][ni], acc[mi][ni], 0, 0, 0);
            }
        }
    }

    // epilogue: + bias[n] - crow[m]; C/D map: col=lane&15, row=quad*4+reg
    // nontemporal stores: keep the 180 MB out-stream from evicting Bp in LLC
#pragma unroll
    for (int mi = 0; mi < 8; ++mi) {
        const int m0 = mBase + wm + mi * 16 + quad * 4;
        float cr[4];
#pragma unroll
        for (int r = 0; r < 4; ++r) cr[r] = crow[m0 + r];
#pragma unroll
        for (int ni = 0; ni < 4; ++ni) {
            const int n = nBase + wn + ni * 16 + fm;
            const float bn = bias[n];
#pragma unroll
            for (int r = 0; r < 4; ++r)
                __builtin_nontemporal_store(acc[mi][ni][r] + bn - cr[r],
                                            &out[(size_t)(m0 + r) * N_DIM + n]);
        }
    }
}

// ---------------------------------------------------------------------------
extern "C" void kernel_launch(void* const* d_in, const int* in_sizes, int n_in,
                              void* d_out, int out_size, void* d_ws, size_t ws_size,
                              hipStream_t stream)
{
    const float* x      = (const float*)d_in[0];
    const int*   pw     = (const int*)d_in[1];
    const float* scales = (const float*)d_in[2];
    const float* zps    = (const float*)d_in[3];
    const float* bias   = (const float*)d_in[4];
    float* out = (float*)d_out;

    char* ws = (char*)d_ws;
    bf16_t* xs   = (bf16_t*)ws;               // 4096*4096*2 = 33554432 B
    float*  crow = (float*)(ws + 33554432);   // 4096*4      = 16384 B

    hipLaunchKernelGGL(k_prescale, dim3(M_DIM), dim3(256), 0, stream,
                       x, scales, zps, xs, crow);
    hipLaunchKernelGGL(k_gemm, dim3(N_DIM / 128, M_DIM / 256), dim3(256), 0, stream,
                       (const bf16_t*)xs, pw, bias, crow, out);
}